// Round 1
// baseline (313.275 us; speedup 1.0000x reference)
//
#include <hip/hip_runtime.h>
#include <hip/hip_bf16.h>

#define EPS 1e-5f
#define DW_THRESH 4.0f
#define PW_THRESH 0.001f

typedef __bf16 bf16x8 __attribute__((ext_vector_type(8)));
typedef float f32x4 __attribute__((ext_vector_type(4)));

// ---------------------------------------------------------------------------
// Kernel 1: depthwise 3x3 + bias + bn1 + relu  (fp32 math)
//  - writes y as bf16 in MFMA-B-fragment-friendly layout:
//      ybuf[((b*784 + hw/16)*8 + c/8)*128 + (hw%16)*8 + (c%8)]
//  - plane max |y| -> flags_y[b*64+c] via atomicMax (y >= 0 after relu)
// ---------------------------------------------------------------------------
__global__ __launch_bounds__(256) void k_dw(
    const float* __restrict__ x, const float* __restrict__ dww, const float* __restrict__ dwb,
    const float* __restrict__ g1, const float* __restrict__ b1,
    const float* __restrict__ m1, const float* __restrict__ v1,
    __bf16* __restrict__ ybuf, unsigned* __restrict__ flags_y)
{
    __shared__ float xs[8][18][114];
    __shared__ float wts[8][9];
    __shared__ float sc1[8], bi1[8];
    __shared__ unsigned pm[8];

    const int s   = blockIdx.x;   // 0..6 (16-row strip)
    const int cg  = blockIdx.y;   // 0..7 (channel group of 8)
    const int b   = blockIdx.z;   // 0..31
    const int tid = threadIdx.x;
    const int h0  = s * 16;

    if (tid < 8) {
        int c = cg * 8 + tid;
        float inv = g1[c] * rsqrtf(v1[c] + EPS);
        sc1[tid] = inv;
        bi1[tid] = dwb[c] * inv + b1[c] - m1[c] * inv;
        pm[tid]  = 0u;
    }
    if (tid < 72) {
        int c = tid / 9, k = tid % 9;
        wts[c][k] = dww[(cg * 8 + c) * 9 + k];
    }
    // stage x tile with halo: rows h0-1 .. h0+16, cols -1..112 (zero pad)
    for (int i = tid; i < 8 * 18 * 114; i += 256) {
        int c   = i / (18 * 114);
        int rem = i - c * (18 * 114);
        int r   = rem / 114;
        int cc  = rem - r * 114;      // 0..113
        int w   = cc - 1;
        int h   = h0 - 1 + r;
        float v = 0.f;
        if ((unsigned)h < 112u && (unsigned)w < 112u)
            v = x[((b * 64 + cg * 8 + c) * 112 + h) * 112 + w];
        xs[c][r][cc] = v;
    }
    __syncthreads();

    float cmax[8];
#pragma unroll
    for (int c = 0; c < 8; ++c) cmax[c] = 0.f;

#pragma unroll
    for (int k = 0; k < 7; ++k) {
        int pos = k * 256 + tid;     // 0..1791 within strip
        int r   = pos / 112;         // 0..15
        int w   = pos - r * 112;     // 0..111
        int hw  = (h0 + r) * 112 + w;
        int hwblk = hw >> 4;
        int l16   = hw & 15;
        bf16x8 pack;
#pragma unroll
        for (int c = 0; c < 8; ++c) {
            float a = 0.f;
#pragma unroll
            for (int dh = 0; dh < 3; ++dh)
#pragma unroll
                for (int dw2 = 0; dw2 < 3; ++dw2)
                    a = fmaf(xs[c][r + dh][w + dw2], wts[c][dh * 3 + dw2], a);
            float yv = fmaf(a, sc1[c], bi1[c]);
            yv = fmaxf(yv, 0.f);
            cmax[c] = fmaxf(cmax[c], yv);
            pack[c] = (__bf16)yv;
        }
        int off = (((b * 784 + hwblk) * 8 + cg) * 16 + l16) * 8;
        *reinterpret_cast<bf16x8*>(ybuf + off) = pack;
    }
#pragma unroll
    for (int c = 0; c < 8; ++c)
        atomicMax(&pm[c], __float_as_uint(cmax[c]));
    __syncthreads();
    if (tid < 8)
        atomicMax(&flags_y[b * 64 + cg * 8 + tid], pm[tid]);
}

// ---------------------------------------------------------------------------
// Kernel 2: pointwise 1x1 (bf16 MFMA) + bn2 + relu, plane-max -> flags_z
//  block: (hw tile of 128, batch b); 4 waves each 64o x 64hw
//  first channel-cut applied as column mask on W during LDS staging
// ---------------------------------------------------------------------------
__global__ __launch_bounds__(256) void k_pw(
    const float* __restrict__ pww, const float* __restrict__ pwb,
    const float* __restrict__ g2, const float* __restrict__ b2,
    const float* __restrict__ m2, const float* __restrict__ v2,
    const __bf16* __restrict__ ybuf, const unsigned* __restrict__ flags_y,
    float* __restrict__ out, unsigned* __restrict__ flags_z)
{
    __shared__ __bf16 wl[128][72];     // +8 pad: kills ds_read_b128 bank conflict
    __shared__ float s2[128], bb2[128];
    __shared__ float keepf[64];
    __shared__ unsigned pmz[128];

    const int t   = blockIdx.x;        // 0..97 hw tile
    const int b   = blockIdx.y;        // 0..31
    const int tid = threadIdx.x;
    const int hw0 = t * 128;

    if (tid < 64)
        keepf[tid] = (__uint_as_float(flags_y[b * 64 + tid]) < DW_THRESH) ? 0.f : 1.f;
    if (tid < 128) {
        float inv = g2[tid] * rsqrtf(v2[tid] + EPS);
        s2[tid]  = inv;
        bb2[tid] = pwb[tid] * inv + b2[tid] - m2[tid] * inv;
        pmz[tid] = 0u;
    }
    __syncthreads();
    for (int i = tid; i < 8192; i += 256) {
        int o = i >> 6, c = i & 63;
        wl[o][c] = (__bf16)(pww[i] * keepf[c]);
    }
    __syncthreads();

    const int wid = tid >> 6, lane = tid & 63;
    const int wm = wid >> 1, wn = wid & 1;
    const int g = lane >> 4, l16 = lane & 15;

    // A fragments (W) from LDS: lane holds rows l16, k = 8g..8g+7 within 32-k block
    bf16x8 af[4][2];
#pragma unroll
    for (int m = 0; m < 4; ++m)
#pragma unroll
        for (int kb = 0; kb < 2; ++kb)
            af[m][kb] = *reinterpret_cast<const bf16x8*>(&wl[64 * wm + 16 * m + l16][32 * kb + 8 * g]);

    // B fragments (Y) straight from global (fragment-layout ybuf)
    bf16x8 bfr[4][2];
    const int hwblk0 = (hw0 >> 4) + 4 * wn;
#pragma unroll
    for (int q = 0; q < 4; ++q)
#pragma unroll
        for (int kb = 0; kb < 2; ++kb) {
            int off = (((b * 784 + hwblk0 + q) * 8 + (4 * kb + g)) * 16 + l16) * 8;
            bfr[q][kb] = *reinterpret_cast<const bf16x8*>(ybuf + off);
        }

    f32x4 acc[4][4];
#pragma unroll
    for (int m = 0; m < 4; ++m)
#pragma unroll
        for (int q = 0; q < 4; ++q)
            acc[m][q] = (f32x4){0.f, 0.f, 0.f, 0.f};

#pragma unroll
    for (int kb = 0; kb < 2; ++kb)
#pragma unroll
        for (int m = 0; m < 4; ++m)
#pragma unroll
            for (int q = 0; q < 4; ++q)
                acc[m][q] = __builtin_amdgcn_mfma_f32_16x16x32_bf16(
                    af[m][kb], bfr[q][kb], acc[m][q], 0, 0, 0);

    // epilogue: bn2 + relu, store, plane-max reduce
#pragma unroll
    for (int m = 0; m < 4; ++m) {
#pragma unroll
        for (int r = 0; r < 4; ++r) {
            int o = 64 * wm + 16 * m + 4 * g + r;
            float sc = s2[o], bi = bb2[o];
            float mx = 0.f;
#pragma unroll
            for (int q = 0; q < 4; ++q) {
                float val = fmaxf(fmaf(acc[m][q][r], sc, bi), 0.f);
                mx = fmaxf(mx, val);
                out[(b * 128 + o) * 12544 + hw0 + 64 * wn + 16 * q + l16] = val;
            }
#pragma unroll
            for (int d = 1; d < 16; d <<= 1)
                mx = fmaxf(mx, __shfl_xor(mx, d, 64));
            if (l16 == 0)
                atomicMax(&pmz[o], __float_as_uint(mx));
        }
    }
    __syncthreads();
    if (tid < 128)
        atomicMax(&flags_z[b * 128 + tid], pmz[tid]);
}

// ---------------------------------------------------------------------------
// Kernel 3: zero planes whose post-relu max < PW_THRESH
// ---------------------------------------------------------------------------
__global__ __launch_bounds__(256) void k_cut(
    const unsigned* __restrict__ flags_z, float* __restrict__ out)
{
    int p = blockIdx.x;   // b*128 + o
    if (__uint_as_float(flags_z[p]) >= PW_THRESH) return;
    int base = p * 12544;
    for (int i = threadIdx.x; i < 12544; i += 256)
        out[base + i] = 0.f;
}

// ---------------------------------------------------------------------------
extern "C" void kernel_launch(void* const* d_in, const int* in_sizes, int n_in,
                              void* d_out, int out_size, void* d_ws, size_t ws_size,
                              hipStream_t stream)
{
    const float* x   = (const float*)d_in[0];
    const float* dww = (const float*)d_in[1];
    const float* dwb = (const float*)d_in[2];
    const float* g1  = (const float*)d_in[3];
    const float* b1  = (const float*)d_in[4];
    const float* m1  = (const float*)d_in[5];
    const float* v1  = (const float*)d_in[6];
    const float* pww = (const float*)d_in[7];
    const float* pwb = (const float*)d_in[8];
    const float* g2  = (const float*)d_in[9];
    const float* b2  = (const float*)d_in[10];
    const float* m2  = (const float*)d_in[11];
    const float* v2  = (const float*)d_in[12];
    float* out = (float*)d_out;

    unsigned char* ws = (unsigned char*)d_ws;
    unsigned* flags_y = (unsigned*)ws;              // 2048 u32
    unsigned* flags_z = (unsigned*)(ws + 8192);     // 4096 u32
    __bf16* ybuf      = (__bf16*)(ws + 65536);      // 32*784*8*16*8 bf16 = 49 MB

    hipMemsetAsync(ws, 0, 65536, stream);

    dim3 gdw(7, 8, 32);
    k_dw<<<gdw, 256, 0, stream>>>(x, dww, dwb, g1, b1, m1, v1, ybuf, flags_y);

    dim3 gpw(98, 32);
    k_pw<<<gpw, 256, 0, stream>>>(pww, pwb, g2, b2, m2, v2, ybuf, flags_y, out, flags_z);

    k_cut<<<4096, 256, 0, stream>>>(flags_z, out);
}

// Round 2
// 193.346 us; speedup vs baseline: 1.6203x; 1.6203x over previous
//
#include <hip/hip_runtime.h>
#include <hip/hip_bf16.h>

#define EPS 1e-5f
#define DW_THRESH 4.0f
#define PW_THRESH 0.001f

typedef __bf16 bf16x4 __attribute__((ext_vector_type(4)));
typedef __bf16 bf16x8 __attribute__((ext_vector_type(8)));
typedef float f32x4 __attribute__((ext_vector_type(4)));

// ---------------------------------------------------------------------------
// Kernel 1: depthwise 3x3 + bias + bn1 + relu  (fp32 math)
//  v2: 4 channels/block (LDS 32.8KB -> 4 blocks/CU), batched staging loads
//      (8 in flight), bn1 scale folded into weights, shuffle-reduce plane max.
//  writes y as bf16 in MFMA-B-fragment layout:
//      ybuf[(((b*784 + hw/16)*8 + c/8)*16 + hw%16)*8 + (c%8)]
// ---------------------------------------------------------------------------
__global__ __launch_bounds__(256, 4) void k_dw(
    const float* __restrict__ x, const float* __restrict__ dww, const float* __restrict__ dwb,
    const float* __restrict__ g1, const float* __restrict__ b1,
    const float* __restrict__ m1, const float* __restrict__ v1,
    __bf16* __restrict__ ybuf, unsigned* __restrict__ flags_y)
{
    __shared__ float xs[4][18][114];   // 32,832 B
    __shared__ float wsc[4][9];
    __shared__ float bi1s[4];

    const int s   = blockIdx.x;   // 0..6  (16-row strip)
    const int cg  = blockIdx.y;   // 0..15 (4-channel group)
    const int b   = blockIdx.z;   // 0..31
    const int tid = threadIdx.x;
    const int h0  = s * 16;

    if (tid < 36) {
        int c = tid / 9, k = tid % 9;
        int ch = cg * 4 + c;
        float inv = g1[ch] * rsqrtf(v1[ch] + EPS);
        wsc[c][k] = dww[ch * 9 + k] * inv;
        if (k == 0) bi1s[c] = dwb[ch] * inv + b1[ch] - m1[ch] * inv;
    }

    // stage x tile with halo: rows h0-1..h0+16, cols -1..112 (zero pad)
    // flat size 4*18*114 = 8208; 8 loads in flight per round
    float* xf = &xs[0][0][0];
    for (int base = 0; base < 8208; base += 2048) {
        float v[8];
#pragma unroll
        for (int j = 0; j < 8; ++j) {
            int i = base + j * 256 + tid;
            float val = 0.f;
            if (i < 8208) {
                int c   = i / 2052;            // 18*114
                int rem = i - c * 2052;
                int r   = rem / 114;
                int cc  = rem - r * 114;
                int h   = h0 - 1 + r;
                int w   = cc - 1;
                if ((unsigned)h < 112u && (unsigned)w < 112u)
                    val = x[((b * 64 + cg * 4 + c) * 112 + h) * 112 + w];
            }
            v[j] = val;
        }
#pragma unroll
        for (int j = 0; j < 8; ++j) {
            int i = base + j * 256 + tid;
            if (i < 8208) xf[i] = v[j];
        }
    }
    __syncthreads();

    float cmax[4] = {0.f, 0.f, 0.f, 0.f};
    const int hwbase = s * 1792;
    const int c8 = cg >> 1, half4 = (cg & 1) * 4;

    for (int k = 0; k < 7; ++k) {
        int pos = k * 256 + tid;      // 0..1791
        int r   = pos / 112;          // 0..15
        int w   = pos - r * 112;      // 0..111
        int hw  = hwbase + pos;
        int hwblk = hw >> 4;
        int l16   = hw & 15;
        bf16x4 pack;
#pragma unroll
        for (int c = 0; c < 4; ++c) {
            float a = 0.f;
#pragma unroll
            for (int dh = 0; dh < 3; ++dh)
#pragma unroll
                for (int dw2 = 0; dw2 < 3; ++dw2)
                    a = fmaf(xs[c][r + dh][w + dw2], wsc[c][dh * 3 + dw2], a);
            float yv = fmaxf(a + bi1s[c], 0.f);
            cmax[c] = fmaxf(cmax[c], yv);
            pack[c] = (__bf16)yv;
        }
        int off = (((b * 784 + hwblk) * 8 + c8) * 16 + l16) * 8 + half4;
        *reinterpret_cast<bf16x4*>(ybuf + off) = pack;
    }

    // 64-lane shuffle max reduce, one global atomic per wave per channel
#pragma unroll
    for (int c = 0; c < 4; ++c) {
        float m = cmax[c];
#pragma unroll
        for (int d = 1; d < 64; d <<= 1)
            m = fmaxf(m, __shfl_xor(m, d, 64));
        if ((tid & 63) == 0)
            atomicMax(&flags_y[b * 64 + cg * 4 + c], __float_as_uint(m));
    }
}

// ---------------------------------------------------------------------------
// Kernel 2: pointwise 1x1 (bf16 MFMA) + bn2 + relu, plane-max -> flags_z
//  block: (hw tile of 128, batch b); 4 waves each 64o x 64hw
//  first channel-cut applied as column mask on W during LDS staging
// ---------------------------------------------------------------------------
__global__ __launch_bounds__(256) void k_pw(
    const float* __restrict__ pww, const float* __restrict__ pwb,
    const float* __restrict__ g2, const float* __restrict__ b2,
    const float* __restrict__ m2, const float* __restrict__ v2,
    const __bf16* __restrict__ ybuf, const unsigned* __restrict__ flags_y,
    float* __restrict__ out, unsigned* __restrict__ flags_z)
{
    __shared__ __bf16 wl[128][72];     // +8 pad: kills ds_read_b128 bank conflict
    __shared__ float s2[128], bb2[128];
    __shared__ float keepf[64];
    __shared__ unsigned pmz[128];

    const int t   = blockIdx.x;        // 0..97 hw tile
    const int b   = blockIdx.y;        // 0..31
    const int tid = threadIdx.x;
    const int hw0 = t * 128;

    if (tid < 64)
        keepf[tid] = (__uint_as_float(flags_y[b * 64 + tid]) < DW_THRESH) ? 0.f : 1.f;
    if (tid < 128) {
        float inv = g2[tid] * rsqrtf(v2[tid] + EPS);
        s2[tid]  = inv;
        bb2[tid] = pwb[tid] * inv + b2[tid] - m2[tid] * inv;
        pmz[tid] = 0u;
    }
    __syncthreads();
    for (int i = tid; i < 8192; i += 256) {
        int o = i >> 6, c = i & 63;
        wl[o][c] = (__bf16)(pww[i] * keepf[c]);
    }
    __syncthreads();

    const int wid = tid >> 6, lane = tid & 63;
    const int wm = wid >> 1, wn = wid & 1;
    const int g = lane >> 4, l16 = lane & 15;

    // A fragments (W) from LDS: lane holds row l16, k = 8g..8g+7 within 32-k block
    bf16x8 af[4][2];
#pragma unroll
    for (int m = 0; m < 4; ++m)
#pragma unroll
        for (int kb = 0; kb < 2; ++kb)
            af[m][kb] = *reinterpret_cast<const bf16x8*>(&wl[64 * wm + 16 * m + l16][32 * kb + 8 * g]);

    // B fragments (Y) straight from global (fragment-layout ybuf)
    bf16x8 bfr[4][2];
    const int hwblk0 = (hw0 >> 4) + 4 * wn;
#pragma unroll
    for (int q = 0; q < 4; ++q)
#pragma unroll
        for (int kb = 0; kb < 2; ++kb) {
            int off = (((b * 784 + hwblk0 + q) * 8 + (4 * kb + g)) * 16 + l16) * 8;
            bfr[q][kb] = *reinterpret_cast<const bf16x8*>(ybuf + off);
        }

    f32x4 acc[4][4];
#pragma unroll
    for (int m = 0; m < 4; ++m)
#pragma unroll
        for (int q = 0; q < 4; ++q)
            acc[m][q] = (f32x4){0.f, 0.f, 0.f, 0.f};

#pragma unroll
    for (int kb = 0; kb < 2; ++kb)
#pragma unroll
        for (int m = 0; m < 4; ++m)
#pragma unroll
            for (int q = 0; q < 4; ++q)
                acc[m][q] = __builtin_amdgcn_mfma_f32_16x16x32_bf16(
                    af[m][kb], bfr[q][kb], acc[m][q], 0, 0, 0);

    // epilogue: bn2 + relu, store, plane-max reduce
#pragma unroll
    for (int m = 0; m < 4; ++m) {
#pragma unroll
        for (int r = 0; r < 4; ++r) {
            int o = 64 * wm + 16 * m + 4 * g + r;
            float sc = s2[o], bi = bb2[o];
            float mx = 0.f;
#pragma unroll
            for (int q = 0; q < 4; ++q) {
                float val = fmaxf(fmaf(acc[m][q][r], sc, bi), 0.f);
                mx = fmaxf(mx, val);
                out[(b * 128 + o) * 12544 + hw0 + 64 * wn + 16 * q + l16] = val;
            }
#pragma unroll
            for (int d = 1; d < 16; d <<= 1)
                mx = fmaxf(mx, __shfl_xor(mx, d, 64));
            if (l16 == 0)
                atomicMax(&pmz[o], __float_as_uint(mx));
        }
    }
    __syncthreads();
    if (tid < 128)
        atomicMax(&flags_z[b * 128 + tid], pmz[tid]);
}

// ---------------------------------------------------------------------------
// Kernel 3: zero planes whose post-relu max < PW_THRESH
// ---------------------------------------------------------------------------
__global__ __launch_bounds__(256) void k_cut(
    const unsigned* __restrict__ flags_z, float* __restrict__ out)
{
    int p = blockIdx.x;   // b*128 + o
    if (__uint_as_float(flags_z[p]) >= PW_THRESH) return;
    int base = p * 12544;
    for (int i = threadIdx.x; i < 12544; i += 256)
        out[base + i] = 0.f;
}

// ---------------------------------------------------------------------------
extern "C" void kernel_launch(void* const* d_in, const int* in_sizes, int n_in,
                              void* d_out, int out_size, void* d_ws, size_t ws_size,
                              hipStream_t stream)
{
    const float* x   = (const float*)d_in[0];
    const float* dww = (const float*)d_in[1];
    const float* dwb = (const float*)d_in[2];
    const float* g1  = (const float*)d_in[3];
    const float* b1  = (const float*)d_in[4];
    const float* m1  = (const float*)d_in[5];
    const float* v1  = (const float*)d_in[6];
    const float* pww = (const float*)d_in[7];
    const float* pwb = (const float*)d_in[8];
    const float* g2  = (const float*)d_in[9];
    const float* b2  = (const float*)d_in[10];
    const float* m2  = (const float*)d_in[11];
    const float* v2  = (const float*)d_in[12];
    float* out = (float*)d_out;

    unsigned char* ws = (unsigned char*)d_ws;
    unsigned* flags_y = (unsigned*)ws;              // 2048 u32
    unsigned* flags_z = (unsigned*)(ws + 8192);     // 4096 u32
    __bf16* ybuf      = (__bf16*)(ws + 65536);      // 32*784*1024 bf16 = 51.4 MB

    hipMemsetAsync(ws, 0, 65536, stream);

    dim3 gdw(7, 16, 32);
    k_dw<<<gdw, 256, 0, stream>>>(x, dww, dwb, g1, b1, m1, v1, ybuf, flags_y);

    dim3 gpw(98, 32);
    k_pw<<<gpw, 256, 0, stream>>>(pww, pwb, g2, b2, m2, v2, ybuf, flags_y, out, flags_z);

    k_cut<<<4096, 256, 0, stream>>>(flags_z, out);
}

// Round 3
// 122.424 us; speedup vs baseline: 2.5589x; 1.5793x over previous
//
#include <hip/hip_runtime.h>
#include <hip/hip_bf16.h>

#define EPS 1e-5f
#define DW_THRESH 4.0f
#define PW_THRESH 0.001f

typedef __bf16 bf16x4 __attribute__((ext_vector_type(4)));
typedef __bf16 bf16x8 __attribute__((ext_vector_type(8)));
typedef float f32x4 __attribute__((ext_vector_type(4)));

// ---------------------------------------------------------------------------
// Kernel 1: depthwise 3x3 + bias + bn1 + relu  (fp32 math)
//  v3: async global->LDS staging (global_load_lds dwordx4, per-lane source,
//      zero-page for halo/tails -> branch-free conv), 4-wide sliding-window
//      compute with ds_read_b128.
//  LDS x tile: xs[4][19][128]  (row 0 = pad row; data rows 1..18 = h0-1..h0+16;
//      cols 0..111 = data, cols 112..127 = zeros staged from zero page)
//  writes y as bf16 in MFMA-B-fragment layout:
//      ybuf[(((b*784 + hw/16)*8 + c/8)*16 + hw%16)*8 + (c%8)]
// ---------------------------------------------------------------------------
__global__ __launch_bounds__(256, 4) void k_dw(
    const float* __restrict__ x, const float* __restrict__ dww, const float* __restrict__ dwb,
    const float* __restrict__ g1, const float* __restrict__ b1,
    const float* __restrict__ m1, const float* __restrict__ v1,
    const float* __restrict__ zp,
    __bf16* __restrict__ ybuf, unsigned* __restrict__ flags_y)
{
    __shared__ float xs[4][19][128];   // 38,912 B
    __shared__ float wsc[4][9];
    __shared__ float bi1s[4];

    const int s   = blockIdx.x;   // 0..6  (16-row strip)
    const int cg  = blockIdx.y;   // 0..15 (4-channel group)
    const int b   = blockIdx.z;   // 0..31
    const int tid = threadIdx.x;
    const int h0  = s * 16;

    if (tid < 36) {
        int c = tid / 9, k = tid % 9;
        int ch = cg * 4 + c;
        float inv = g1[ch] * rsqrtf(v1[ch] + EPS);
        wsc[c][k] = dww[ch * 9 + k] * inv;
        if (k == 0) bi1s[c] = dwb[ch] * inv + b1[ch] - m1[ch] * inv;
    }
    // zero the tail of each channel's pad row (read as "col -1 of data row 0")
    if (tid < 16) xs[tid >> 2][0][124 + (tid & 3)] = 0.f;

    // ---- async staging: 72 rows (4c x 18), 2 rows per wave-issue ----------
    const int lane  = tid & 63;
    const int wid   = tid >> 6;
    const int lane5 = lane & 31;
    const int half  = lane >> 5;
    const float* xc_base = x + ((long)(b * 64 + cg * 4) * 12544);
#pragma unroll
    for (int issue = 0; issue < 9; ++issue) {
        int rowIdx0 = issue * 8 + wid * 2;       // even; never straddles c
        int c0 = rowIdx0 / 18;
        int j0 = rowIdx0 - c0 * 18;
        int h  = h0 - 1 + j0 + half;             // per-lane (half)
        const float* src = ((unsigned)h < 112u && lane5 < 28)
            ? (xc_base + c0 * 12544 + h * 112 + lane5 * 4)
            : (zp + lane5 * 4);
        __builtin_amdgcn_global_load_lds(
            (const __attribute__((address_space(1))) void*)src,
            (__attribute__((address_space(3))) void*)(&xs[c0][1 + j0][0]),
            16, 0, 0);
    }
    __syncthreads();

    // ---- compute: 448 quads (16 rows x 28 w-quads), 4 channels each -------
    float cmax[4] = {0.f, 0.f, 0.f, 0.f};
    const int hwbase = h0 * 112;
    const int c8 = cg >> 1, half4 = (cg & 1) * 4;

#pragma unroll
    for (int it = 0; it < 2; ++it) {
        int qid = it * 256 + tid;
        if (qid >= 448) break;                   // wave-uniform (lanes 192.. of it=1)
        int r  = qid / 28;                       // 0..15
        int w0 = (qid - r * 28) * 4;             // 0,4,...,108

        float yv[4][4];
#pragma unroll
        for (int c = 0; c < 4; ++c) {
            float a0 = 0.f, a1 = 0.f, a2 = 0.f, a3 = 0.f;
#pragma unroll
            for (int dh = 0; dh < 3; ++dh) {
                const float* row = &xs[c][1 + r + dh][0];
                f32x4 A = *reinterpret_cast<const f32x4*>(row + w0 - 4);  // need A[3]=col w0-1
                f32x4 B = *reinterpret_cast<const f32x4*>(row + w0);
                f32x4 C = *reinterpret_cast<const f32x4*>(row + w0 + 4);  // need C[0]=col w0+4
                float k0 = wsc[c][dh * 3 + 0];
                float k1 = wsc[c][dh * 3 + 1];
                float k2 = wsc[c][dh * 3 + 2];
                a0 = fmaf(k0, A[3], fmaf(k1, B[0], fmaf(k2, B[1], a0)));
                a1 = fmaf(k0, B[0], fmaf(k1, B[1], fmaf(k2, B[2], a1)));
                a2 = fmaf(k0, B[1], fmaf(k1, B[2], fmaf(k2, B[3], a2)));
                a3 = fmaf(k0, B[2], fmaf(k1, B[3], fmaf(k2, C[0], a3)));
            }
            float bi = bi1s[c];
            yv[c][0] = fmaxf(a0 + bi, 0.f);
            yv[c][1] = fmaxf(a1 + bi, 0.f);
            yv[c][2] = fmaxf(a2 + bi, 0.f);
            yv[c][3] = fmaxf(a3 + bi, 0.f);
            cmax[c] = fmaxf(cmax[c],
                      fmaxf(fmaxf(yv[c][0], yv[c][1]), fmaxf(yv[c][2], yv[c][3])));
        }

        int hw    = hwbase + r * 112 + w0;
        int hwblk = hw >> 4;
        int l16   = hw & 15;                      // multiple of 4; l16+3 <= 15
        long base = (((long)(b * 784 + hwblk) * 8 + c8) * 16 + l16) * 8 + half4;
#pragma unroll
        for (int i = 0; i < 4; ++i) {
            bf16x4 pack = { (__bf16)yv[0][i], (__bf16)yv[1][i],
                            (__bf16)yv[2][i], (__bf16)yv[3][i] };
            *reinterpret_cast<bf16x4*>(ybuf + base + i * 8) = pack;
        }
    }

    // 64-lane shuffle max reduce, one global atomic per wave per channel
#pragma unroll
    for (int c = 0; c < 4; ++c) {
        float m = cmax[c];
#pragma unroll
        for (int d = 1; d < 64; d <<= 1)
            m = fmaxf(m, __shfl_xor(m, d, 64));
        if (lane == 0)
            atomicMax(&flags_y[b * 64 + cg * 4 + c], __float_as_uint(m));
    }
}

// ---------------------------------------------------------------------------
// Kernel 2: pointwise 1x1 (bf16 MFMA) + bn2 + relu, plane-max -> flags_z
//  block: (hw tile of 128, batch b); 4 waves each 64o x 64hw
//  first channel-cut applied as column mask on W during LDS staging
// ---------------------------------------------------------------------------
__global__ __launch_bounds__(256) void k_pw(
    const float* __restrict__ pww, const float* __restrict__ pwb,
    const float* __restrict__ g2, const float* __restrict__ b2,
    const float* __restrict__ m2, const float* __restrict__ v2,
    const __bf16* __restrict__ ybuf, const unsigned* __restrict__ flags_y,
    float* __restrict__ out, unsigned* __restrict__ flags_z)
{
    __shared__ __bf16 wl[128][72];     // +8 pad: kills ds_read_b128 bank conflict
    __shared__ float s2[128], bb2[128];
    __shared__ float keepf[64];
    __shared__ unsigned pmz[128];

    const int t   = blockIdx.x;        // 0..97 hw tile
    const int b   = blockIdx.y;        // 0..31
    const int tid = threadIdx.x;
    const int hw0 = t * 128;

    if (tid < 64)
        keepf[tid] = (__uint_as_float(flags_y[b * 64 + tid]) < DW_THRESH) ? 0.f : 1.f;
    if (tid < 128) {
        float inv = g2[tid] * rsqrtf(v2[tid] + EPS);
        s2[tid]  = inv;
        bb2[tid] = pwb[tid] * inv + b2[tid] - m2[tid] * inv;
        pmz[tid] = 0u;
    }
    __syncthreads();
    for (int i = tid; i < 8192; i += 256) {
        int o = i >> 6, c = i & 63;
        wl[o][c] = (__bf16)(pww[i] * keepf[c]);
    }
    __syncthreads();

    const int wid = tid >> 6, lane = tid & 63;
    const int wm = wid >> 1, wn = wid & 1;
    const int g = lane >> 4, l16 = lane & 15;

    // A fragments (W) from LDS: lane holds row l16, k = 8g..8g+7 within 32-k block
    bf16x8 af[4][2];
#pragma unroll
    for (int m = 0; m < 4; ++m)
#pragma unroll
        for (int kb = 0; kb < 2; ++kb)
            af[m][kb] = *reinterpret_cast<const bf16x8*>(&wl[64 * wm + 16 * m + l16][32 * kb + 8 * g]);

    // B fragments (Y) straight from global (fragment-layout ybuf)
    bf16x8 bfr[4][2];
    const int hwblk0 = (hw0 >> 4) + 4 * wn;
#pragma unroll
    for (int q = 0; q < 4; ++q)
#pragma unroll
        for (int kb = 0; kb < 2; ++kb) {
            int off = (((b * 784 + hwblk0 + q) * 8 + (4 * kb + g)) * 16 + l16) * 8;
            bfr[q][kb] = *reinterpret_cast<const bf16x8*>(ybuf + off);
        }

    f32x4 acc[4][4];
#pragma unroll
    for (int m = 0; m < 4; ++m)
#pragma unroll
        for (int q = 0; q < 4; ++q)
            acc[m][q] = (f32x4){0.f, 0.f, 0.f, 0.f};

#pragma unroll
    for (int kb = 0; kb < 2; ++kb)
#pragma unroll
        for (int m = 0; m < 4; ++m)
#pragma unroll
            for (int q = 0; q < 4; ++q)
                acc[m][q] = __builtin_amdgcn_mfma_f32_16x16x32_bf16(
                    af[m][kb], bfr[q][kb], acc[m][q], 0, 0, 0);

    // epilogue: bn2 + relu, store, plane-max reduce
#pragma unroll
    for (int m = 0; m < 4; ++m) {
#pragma unroll
        for (int r = 0; r < 4; ++r) {
            int o = 64 * wm + 16 * m + 4 * g + r;
            float sc = s2[o], bi = bb2[o];
            float mx = 0.f;
#pragma unroll
            for (int q = 0; q < 4; ++q) {
                float val = fmaxf(fmaf(acc[m][q][r], sc, bi), 0.f);
                mx = fmaxf(mx, val);
                out[(b * 128 + o) * 12544 + hw0 + 64 * wn + 16 * q + l16] = val;
            }
#pragma unroll
            for (int d = 1; d < 16; d <<= 1)
                mx = fmaxf(mx, __shfl_xor(mx, d, 64));
            if (l16 == 0)
                atomicMax(&pmz[o], __float_as_uint(mx));
        }
    }
    __syncthreads();
    if (tid < 128)
        atomicMax(&flags_z[b * 128 + tid], pmz[tid]);
}

// ---------------------------------------------------------------------------
// Kernel 3: zero planes whose post-relu max < PW_THRESH
// ---------------------------------------------------------------------------
__global__ __launch_bounds__(256) void k_cut(
    const unsigned* __restrict__ flags_z, float* __restrict__ out)
{
    int p = blockIdx.x;   // b*128 + o
    if (__uint_as_float(flags_z[p]) >= PW_THRESH) return;
    int base = p * 12544;
    for (int i = threadIdx.x; i < 12544; i += 256)
        out[base + i] = 0.f;
}

// ---------------------------------------------------------------------------
extern "C" void kernel_launch(void* const* d_in, const int* in_sizes, int n_in,
                              void* d_out, int out_size, void* d_ws, size_t ws_size,
                              hipStream_t stream)
{
    const float* x   = (const float*)d_in[0];
    const float* dww = (const float*)d_in[1];
    const float* dwb = (const float*)d_in[2];
    const float* g1  = (const float*)d_in[3];
    const float* b1  = (const float*)d_in[4];
    const float* m1  = (const float*)d_in[5];
    const float* v1  = (const float*)d_in[6];
    const float* pww = (const float*)d_in[7];
    const float* pwb = (const float*)d_in[8];
    const float* g2  = (const float*)d_in[9];
    const float* b2  = (const float*)d_in[10];
    const float* m2  = (const float*)d_in[11];
    const float* v2  = (const float*)d_in[12];
    float* out = (float*)d_out;

    unsigned char* ws = (unsigned char*)d_ws;
    unsigned* flags_y = (unsigned*)ws;              // 2048 u32  @ 0
    unsigned* flags_z = (unsigned*)(ws + 8192);     // 4096 u32  @ 8192
    const float* zp   = (const float*)(ws + 24576); // 1 KB zero page
    __bf16* ybuf      = (__bf16*)(ws + 65536);      // 32*784*1024 bf16 = 51.4 MB

    hipMemsetAsync(ws, 0, 25600, stream);

    dim3 gdw(7, 16, 32);
    k_dw<<<gdw, 256, 0, stream>>>(x, dww, dwb, g1, b1, m1, v1, zp, ybuf, flags_y);

    dim3 gpw(98, 32);
    k_pw<<<gpw, 256, 0, stream>>>(pww, pwb, g2, b2, m2, v2, ybuf, flags_y, out, flags_z);

    k_cut<<<4096, 256, 0, stream>>>(flags_z, out);
}

// Round 4
// 117.079 us; speedup vs baseline: 2.6758x; 1.0457x over previous
//
#include <hip/hip_runtime.h>
#include <hip/hip_bf16.h>

#define EPS 1e-5f
#define DW_THRESH 4.0f
#define PW_THRESH 0.001f

typedef __bf16 bf16x4 __attribute__((ext_vector_type(4)));
typedef __bf16 bf16x8 __attribute__((ext_vector_type(8)));
typedef float f32x4 __attribute__((ext_vector_type(4)));

// ---------------------------------------------------------------------------
// Kernel 1: depthwise 3x3 + bias + bn1 + relu  (fp32 math)
//  v4: ybuf layout regrouped to channel-quads so each block owns whole 128B
//      regions and each thread stores 32 contiguous bytes (2x bf16x8).
//  ybuf[(((b*784 + hw/16)*16 + c/4)*16 + hw%16)*4 + (c%4)]
// ---------------------------------------------------------------------------
__global__ __launch_bounds__(256, 4) void k_dw(
    const float* __restrict__ x, const float* __restrict__ dww, const float* __restrict__ dwb,
    const float* __restrict__ g1, const float* __restrict__ b1,
    const float* __restrict__ m1, const float* __restrict__ v1,
    const float* __restrict__ zp,
    __bf16* __restrict__ ybuf, unsigned* __restrict__ flags_y)
{
    __shared__ float xs[4][19][128];   // 38,912 B
    __shared__ float wsc[4][9];
    __shared__ float bi1s[4];

    const int s   = blockIdx.x;   // 0..6  (16-row strip)
    const int cg  = blockIdx.y;   // 0..15 (4-channel group == ybuf c/4 group)
    const int b   = blockIdx.z;   // 0..31
    const int tid = threadIdx.x;
    const int h0  = s * 16;

    if (tid < 36) {
        int c = tid / 9, k = tid % 9;
        int ch = cg * 4 + c;
        float inv = g1[ch] * rsqrtf(v1[ch] + EPS);
        wsc[c][k] = dww[ch * 9 + k] * inv;
        if (k == 0) bi1s[c] = dwb[ch] * inv + b1[ch] - m1[ch] * inv;
    }
    // zero the tail of each channel's pad row (read as "col -1 of data row 0")
    if (tid < 16) xs[tid >> 2][0][124 + (tid & 3)] = 0.f;

    // ---- async staging: 72 rows (4c x 18), 2 rows per wave-issue ----------
    const int lane  = tid & 63;
    const int wid   = tid >> 6;
    const int lane5 = lane & 31;
    const int half  = lane >> 5;
    const float* xc_base = x + ((long)(b * 64 + cg * 4) * 12544);
#pragma unroll
    for (int issue = 0; issue < 9; ++issue) {
        int rowIdx0 = issue * 8 + wid * 2;       // even; never straddles c
        int c0 = rowIdx0 / 18;
        int j0 = rowIdx0 - c0 * 18;
        int h  = h0 - 1 + j0 + half;             // per-lane (half)
        const float* src = ((unsigned)h < 112u && lane5 < 28)
            ? (xc_base + c0 * 12544 + h * 112 + lane5 * 4)
            : (zp + lane5 * 4);
        __builtin_amdgcn_global_load_lds(
            (const __attribute__((address_space(1))) void*)src,
            (__attribute__((address_space(3))) void*)(&xs[c0][1 + j0][0]),
            16, 0, 0);
    }
    __syncthreads();

    // ---- compute: 448 quads (16 rows x 28 w-quads), 4 channels each -------
    float cmax[4] = {0.f, 0.f, 0.f, 0.f};
    const int hwbase = h0 * 112;

#pragma unroll
    for (int it = 0; it < 2; ++it) {
        int qid = it * 256 + tid;
        if (qid >= 448) break;                   // wave-uniform (lanes 192.. of it=1)
        int r  = qid / 28;                       // 0..15
        int w0 = (qid - r * 28) * 4;             // 0,4,...,108

        float yv[4][4];
#pragma unroll
        for (int c = 0; c < 4; ++c) {
            float a0 = 0.f, a1 = 0.f, a2 = 0.f, a3 = 0.f;
#pragma unroll
            for (int dh = 0; dh < 3; ++dh) {
                const float* row = &xs[c][1 + r + dh][0];
                f32x4 A = *reinterpret_cast<const f32x4*>(row + w0 - 4);  // need A[3]=col w0-1
                f32x4 B = *reinterpret_cast<const f32x4*>(row + w0);
                f32x4 C = *reinterpret_cast<const f32x4*>(row + w0 + 4);  // need C[0]=col w0+4
                float k0 = wsc[c][dh * 3 + 0];
                float k1 = wsc[c][dh * 3 + 1];
                float k2 = wsc[c][dh * 3 + 2];
                a0 = fmaf(k0, A[3], fmaf(k1, B[0], fmaf(k2, B[1], a0)));
                a1 = fmaf(k0, B[0], fmaf(k1, B[1], fmaf(k2, B[2], a1)));
                a2 = fmaf(k0, B[1], fmaf(k1, B[2], fmaf(k2, B[3], a2)));
                a3 = fmaf(k0, B[2], fmaf(k1, B[3], fmaf(k2, C[0], a3)));
            }
            float bi = bi1s[c];
            yv[c][0] = fmaxf(a0 + bi, 0.f);
            yv[c][1] = fmaxf(a1 + bi, 0.f);
            yv[c][2] = fmaxf(a2 + bi, 0.f);
            yv[c][3] = fmaxf(a3 + bi, 0.f);
            cmax[c] = fmaxf(cmax[c],
                      fmaxf(fmaxf(yv[c][0], yv[c][1]), fmaxf(yv[c][2], yv[c][3])));
        }

        int hw    = hwbase + r * 112 + w0;
        int hwblk = hw >> 4;
        int l16   = hw & 15;                      // multiple of 4; l16+3 <= 15
        long base = (((long)(b * 784 + hwblk) * 16 + cg) * 16 + l16) * 4;
        bf16x8 pk0 = { (__bf16)yv[0][0], (__bf16)yv[1][0], (__bf16)yv[2][0], (__bf16)yv[3][0],
                       (__bf16)yv[0][1], (__bf16)yv[1][1], (__bf16)yv[2][1], (__bf16)yv[3][1] };
        bf16x8 pk1 = { (__bf16)yv[0][2], (__bf16)yv[1][2], (__bf16)yv[2][2], (__bf16)yv[3][2],
                       (__bf16)yv[0][3], (__bf16)yv[1][3], (__bf16)yv[2][3], (__bf16)yv[3][3] };
        *reinterpret_cast<bf16x8*>(ybuf + base)     = pk0;
        *reinterpret_cast<bf16x8*>(ybuf + base + 8) = pk1;
    }

    // 64-lane shuffle max reduce, one global atomic per wave per channel
#pragma unroll
    for (int c = 0; c < 4; ++c) {
        float m = cmax[c];
#pragma unroll
        for (int d = 1; d < 64; d <<= 1)
            m = fmaxf(m, __shfl_xor(m, d, 64));
        if (lane == 0)
            atomicMax(&flags_y[b * 64 + cg * 4 + c], __float_as_uint(m));
    }
}

// ---------------------------------------------------------------------------
// Kernel 2: pointwise 1x1 (bf16 MFMA) + bn2 + relu, plane-max -> flags_z
//  block: (hw tile of 128, batch b); 4 waves each 64o x 64hw
//  first channel-cut applied as column mask on W during LDS staging
// ---------------------------------------------------------------------------
__global__ __launch_bounds__(256) void k_pw(
    const float* __restrict__ pww, const float* __restrict__ pwb,
    const float* __restrict__ g2, const float* __restrict__ b2,
    const float* __restrict__ m2, const float* __restrict__ v2,
    const __bf16* __restrict__ ybuf, const unsigned* __restrict__ flags_y,
    float* __restrict__ out, unsigned* __restrict__ flags_z)
{
    __shared__ __bf16 wl[128][72];     // +8 pad: kills ds_read_b128 bank conflict
    __shared__ float s2[128], bb2[128];
    __shared__ float keepf[64];
    __shared__ unsigned pmz[128];

    const int t   = blockIdx.x;        // 0..97 hw tile
    const int b   = blockIdx.y;        // 0..31
    const int tid = threadIdx.x;
    const int hw0 = t * 128;

    if (tid < 64)
        keepf[tid] = (__uint_as_float(flags_y[b * 64 + tid]) < DW_THRESH) ? 0.f : 1.f;
    if (tid < 128) {
        float inv = g2[tid] * rsqrtf(v2[tid] + EPS);
        s2[tid]  = inv;
        bb2[tid] = pwb[tid] * inv + b2[tid] - m2[tid] * inv;
        pmz[tid] = 0u;
    }
    __syncthreads();
    for (int i = tid; i < 8192; i += 256) {
        int o = i >> 6, c = i & 63;
        wl[o][c] = (__bf16)(pww[i] * keepf[c]);
    }
    __syncthreads();

    const int wid = tid >> 6, lane = tid & 63;
    const int wm = wid >> 1, wn = wid & 1;
    const int g = lane >> 4, l16 = lane & 15;

    // A fragments (W) from LDS: lane holds row l16, k = 8g..8g+7 within 32-k block
    bf16x8 af[4][2];
#pragma unroll
    for (int m = 0; m < 4; ++m)
#pragma unroll
        for (int kb = 0; kb < 2; ++kb)
            af[m][kb] = *reinterpret_cast<const bf16x8*>(&wl[64 * wm + 16 * m + l16][32 * kb + 8 * g]);

    // B fragments (Y) straight from global (channel-quad fragment layout)
    bf16x8 bfr[4][2];
    const int hwblk0 = (hw0 >> 4) + 4 * wn;
#pragma unroll
    for (int q = 0; q < 4; ++q)
#pragma unroll
        for (int kb = 0; kb < 2; ++kb) {
            long rb = ((long)(b * 784 + hwblk0 + q)) * 16;
            int grp = kb * 8 + 2 * g;
            bf16x4 lo = *reinterpret_cast<const bf16x4*>(ybuf + (rb + grp)     * 64 + l16 * 4);
            bf16x4 hi = *reinterpret_cast<const bf16x4*>(ybuf + (rb + grp + 1) * 64 + l16 * 4);
            bfr[q][kb] = (bf16x8){ lo[0], lo[1], lo[2], lo[3],
                                   hi[0], hi[1], hi[2], hi[3] };
        }

    f32x4 acc[4][4];
#pragma unroll
    for (int m = 0; m < 4; ++m)
#pragma unroll
        for (int q = 0; q < 4; ++q)
            acc[m][q] = (f32x4){0.f, 0.f, 0.f, 0.f};

#pragma unroll
    for (int kb = 0; kb < 2; ++kb)
#pragma unroll
        for (int m = 0; m < 4; ++m)
#pragma unroll
            for (int q = 0; q < 4; ++q)
                acc[m][q] = __builtin_amdgcn_mfma_f32_16x16x32_bf16(
                    af[m][kb], bfr[q][kb], acc[m][q], 0, 0, 0);

    // epilogue: bn2 + relu, store, plane-max reduce
#pragma unroll
    for (int m = 0; m < 4; ++m) {
#pragma unroll
        for (int r = 0; r < 4; ++r) {
            int o = 64 * wm + 16 * m + 4 * g + r;
            float sc = s2[o], bi = bb2[o];
            float mx = 0.f;
#pragma unroll
            for (int q = 0; q < 4; ++q) {
                float val = fmaxf(fmaf(acc[m][q][r], sc, bi), 0.f);
                mx = fmaxf(mx, val);
                out[(b * 128 + o) * 12544 + hw0 + 64 * wn + 16 * q + l16] = val;
            }
#pragma unroll
            for (int d = 1; d < 16; d <<= 1)
                mx = fmaxf(mx, __shfl_xor(mx, d, 64));
            if (l16 == 0)
                atomicMax(&pmz[o], __float_as_uint(mx));
        }
    }
    __syncthreads();
    if (tid < 128)
        atomicMax(&flags_z[b * 128 + tid], pmz[tid]);
}

// ---------------------------------------------------------------------------
// Kernel 3: zero planes whose post-relu max < PW_THRESH
// ---------------------------------------------------------------------------
__global__ __launch_bounds__(256) void k_cut(
    const unsigned* __restrict__ flags_z, float* __restrict__ out)
{
    int p = blockIdx.x;   // b*128 + o
    if (__uint_as_float(flags_z[p]) >= PW_THRESH) return;
    int base = p * 12544;
    for (int i = threadIdx.x; i < 12544; i += 256)
        out[base + i] = 0.f;
}

// ---------------------------------------------------------------------------
extern "C" void kernel_launch(void* const* d_in, const int* in_sizes, int n_in,
                              void* d_out, int out_size, void* d_ws, size_t ws_size,
                              hipStream_t stream)
{
    const float* x   = (const float*)d_in[0];
    const float* dww = (const float*)d_in[1];
    const float* dwb = (const float*)d_in[2];
    const float* g1  = (const float*)d_in[3];
    const float* b1  = (const float*)d_in[4];
    const float* m1  = (const float*)d_in[5];
    const float* v1  = (const float*)d_in[6];
    const float* pww = (const float*)d_in[7];
    const float* pwb = (const float*)d_in[8];
    const float* g2  = (const float*)d_in[9];
    const float* b2  = (const float*)d_in[10];
    const float* m2  = (const float*)d_in[11];
    const float* v2  = (const float*)d_in[12];
    float* out = (float*)d_out;

    unsigned char* ws = (unsigned char*)d_ws;
    unsigned* flags_y = (unsigned*)ws;              // 2048 u32  @ 0
    unsigned* flags_z = (unsigned*)(ws + 8192);     // 4096 u32  @ 8192
    const float* zp   = (const float*)(ws + 24576); // 1 KB zero page
    __bf16* ybuf      = (__bf16*)(ws + 65536);      // 32*784*1024 bf16 = 51.4 MB

    hipMemsetAsync(ws, 0, 25600, stream);

    dim3 gdw(7, 16, 32);
    k_dw<<<gdw, 256, 0, stream>>>(x, dww, dwb, g1, b1, m1, v1, zp, ybuf, flags_y);

    dim3 gpw(98, 32);
    k_pw<<<gpw, 256, 0, stream>>>(pww, pwb, g2, b2, m2, v2, ybuf, flags_y, out, flags_z);

    k_cut<<<4096, 256, 0, stream>>>(flags_z, out);
}